// Round 7
// baseline (72.618 us; speedup 1.0000x reference)
//
#include <hip/hip_runtime.h>
#include <math.h>

// single_channel_interp (B=8, D=64, T=512, O=256) — R6
// R5 (mask compaction, broadcast-LDS, exp2 log2-domain) + 4 o's per lane:
// every wave covers all 256 o's (o = lane + {0,64,128,192}), so the 8 waves
// split t 8 ways (~45 live t's each). Broadcast ds_read_b128 count halves
// vs R5 -> LDS pipe ~2.8us/CU, balanced with trans (~2.4) and VALU (~2.1).
// Partials [8][4][256] = 32KB LDS; final reduce split: tid<256 -> {y,w},
// tid>=256 -> {y_trans}.

namespace {
constexpr int kB = 8, kD = 64, kT = 512, kO = 256;
constexpr int kTH = 512;          // 8 waves
constexpr float kLOG2E = 1.4426950408889634f;
constexpr float kLN2   = 0.6931471805599453f;
}

__device__ __forceinline__ float2 pkfma(float2 a, float b, float2 c) {
    return make_float2(fmaf(a.x, b, c.x), fmaf(a.y, b, c.y));
}
__device__ __forceinline__ float2 pkadd(float2 a, float2 b) {
    return make_float2(a.x + b.x, a.y + b.y);
}

__global__ __launch_bounds__(kTH, 8) void interp_kernel(
    const float* __restrict__ x,     // (B, 3D, T)
    const float* __restrict__ grid,  // (B, O)
    const float* __restrict__ kern,  // (D,)
    float* __restrict__ out)         // (B, 3D, O)
{
    // During loop: [0:512)=u, [512:1024)=w, [1024:1536)=v.
    // Epilogue: reused as partials [chunk 8][quantity 4][o 256] = 8192 floats.
    __shared__ __align__(16) float smem[8192 + 8];
    float* s_u   = smem;
    float* s_w   = smem + kT;
    float* s_v   = smem + 2 * kT;
    float* s_cnt = smem + 8192;     // 8 per-wave live counts

    const int tid  = threadIdx.x;
    const int lane = tid & 63;
    const int wv   = tid >> 6;       // 0..7 = t-chunk
    const int o0   = lane;           // this lane's 4 o's
    const int o1   = lane + 64;
    const int o2   = lane + 128;
    const int o3   = lane + 192;

    const int bd = blockIdx.x;
    const int b  = bd >> 6;
    const int d  = bd & (kD - 1);

    const float* base = x + (size_t)b * (3 * kD * kT);
    const float* Vrow = base + (size_t)d * kT;
    const float* Mrow = base + (size_t)(kD + d) * kT;
    const float* Trow = base + (size_t)(2 * kD + d) * kT;

    const float k     = kern[d];
    const float alpha = fmaxf(k, 0.0f) + log1pf(expf(-fabsf(k)));
    const float a2    = alpha * kLOG2E;

    // ---- Stage + compact (thread i <-> t=i, coalesced) ----
    const float tt = Trow[tid];
    const float mm = Mrow[tid];
    const float vv = Vrow[tid];
    const bool keep = (mm != 0.0f);
    const unsigned long long ball = __ballot(keep);
    if (lane == 0) s_cnt[wv] = (float)__popcll(ball);
    __syncthreads();

    int bsum = 0, total = 0;
    #pragma unroll
    for (int j = 0; j < 8; ++j) {
        const int c = (int)s_cnt[j];
        bsum  += (j < wv) ? c : 0;
        total += c;
    }
    const int padded = (total + 31) & ~31;           // chunk=padded/8 mult of 4

    if (keep) {
        const int pos = bsum + __popcll(ball & ((1ull << lane) - 1ull));
        s_u[pos] = -a2 * tt * tt;                    // live => mask==1 => lm=0
        s_w[pos] = 2.0f * a2 * tt;
        s_v[pos] = vv;
    }
    if (tid >= total && tid < padded) {              // neutral padding
        s_u[tid] = -500.0f;                          // exp2 -> 0 (also x10)
        s_w[tid] = 0.0f;
        s_v[tid] = 0.0f;
    }
    __syncthreads();

    const int gb = b * kO;
    const float2 g01 = make_float2(grid[gb + o0], grid[gb + o1]);
    const float2 g23 = make_float2(grid[gb + o2], grid[gb + o3]);
    const float2 c01 = make_float2(-a2 * g01.x * g01.x, -a2 * g01.y * g01.y);
    const float2 c23 = make_float2(-a2 * g23.x * g23.x, -a2 * g23.y * g23.y);

    float2 l01 = make_float2(0.f, 0.f), l23 = make_float2(0.f, 0.f);
    float2 y01 = make_float2(0.f, 0.f), y23 = make_float2(0.f, 0.f);
    float2 q01 = make_float2(0.f, 0.f), q23 = make_float2(0.f, 0.f);
    float2 z01 = make_float2(0.f, 0.f), z23 = make_float2(0.f, 0.f);

    const int chunk = padded >> 3;                   // multiple of 4
    const int t0 = wv * chunk;
    for (int t = t0; t < t0 + chunk; t += 4) {
        // All 64 lanes read the same LDS address -> broadcast, conflict-free.
        const float4 uu = *(const float4*)(s_u + t);
        const float4 ww = *(const float4*)(s_w + t);
        const float4 vs = *(const float4*)(s_v + t);

        #pragma unroll
        for (int j = 0; j < 4; ++j) {
            const float u = (&uu.x)[j], w = (&ww.x)[j], v = (&vs.x)[j];
            const float2 a01v = pkadd(pkfma(g01, w, make_float2(u, u)), c01);
            const float2 a23v = pkadd(pkfma(g23, w, make_float2(u, u)), c23);
            const float2 e01 = make_float2(__builtin_amdgcn_exp2f(a01v.x),
                                           __builtin_amdgcn_exp2f(a01v.y));
            const float2 e23 = make_float2(__builtin_amdgcn_exp2f(a23v.x),
                                           __builtin_amdgcn_exp2f(a23v.y));
            const float2 E01 = make_float2(__builtin_amdgcn_exp2f(10.0f * a01v.x),
                                           __builtin_amdgcn_exp2f(10.0f * a01v.y));
            const float2 E23 = make_float2(__builtin_amdgcn_exp2f(10.0f * a23v.x),
                                           __builtin_amdgcn_exp2f(10.0f * a23v.y));
            l01 = pkadd(l01, e01);  l23 = pkadd(l23, e23);
            y01 = pkfma(e01, v, y01);  y23 = pkfma(e23, v, y23);
            q01 = pkadd(q01, E01);  q23 = pkadd(q23, E23);
            z01 = pkfma(E01, v, z01);  z23 = pkfma(E23, v, z23);
        }
    }

    // ---- Partials to LDS: sp[chunk][quantity][o] ----
    __syncthreads();
    float (*sp)[4][kO] = (float (*)[4][kO])smem;
    sp[wv][0][o0] = l01.x; sp[wv][0][o1] = l01.y;
    sp[wv][0][o2] = l23.x; sp[wv][0][o3] = l23.y;
    sp[wv][1][o0] = y01.x; sp[wv][1][o1] = y01.y;
    sp[wv][1][o2] = y23.x; sp[wv][1][o3] = y23.y;
    sp[wv][2][o0] = q01.x; sp[wv][2][o1] = q01.y;
    sp[wv][2][o2] = q23.x; sp[wv][2][o3] = q23.y;
    sp[wv][3][o0] = z01.x; sp[wv][3][o1] = z01.y;
    sp[wv][3][o2] = z23.x; sp[wv][3][o3] = z23.y;
    __syncthreads();

    // ---- Final reduce: tid<256 -> y,w ; tid>=256 -> y_trans ----
    float* ob = out + (size_t)b * (3 * kD * kO);
    if (tid < kO) {
        const int o = tid;
        float L = 0.f, Y = 0.f;
        #pragma unroll
        for (int j = 0; j < 8; ++j) { L += sp[j][0][o]; Y += sp[j][1][o]; }
        ob[(size_t)d * kO + o]        = Y / L;
        ob[(size_t)(kD + d) * kO + o] = __builtin_amdgcn_logf(L) * kLN2;
    } else {
        const int o = tid - kO;
        float Q = 0.f, Z = 0.f;
        #pragma unroll
        for (int j = 0; j < 8; ++j) { Q += sp[j][2][o]; Z += sp[j][3][o]; }
        ob[(size_t)(2 * kD + d) * kO + o] = Z / Q;
    }
}

extern "C" void kernel_launch(void* const* d_in, const int* in_sizes, int n_in,
                              void* d_out, int out_size, void* d_ws, size_t ws_size,
                              hipStream_t stream) {
    const float* x    = (const float*)d_in[0];
    const float* grid = (const float*)d_in[1];
    const float* kern = (const float*)d_in[2];
    float* out        = (float*)d_out;
    interp_kernel<<<dim3(kB * kD), dim3(kTH), 0, stream>>>(x, grid, kern, out);
}